// Round 1
// baseline (135.650 us; speedup 1.0000x reference)
//
#include <hip/hip_runtime.h>
#include <stdint.h>

// ---------- types ----------
typedef __attribute__((ext_vector_type(8))) short bf16x8;
typedef __attribute__((ext_vector_type(4))) float f32x4;

// ---------- helpers ----------
__device__ __forceinline__ unsigned short f2bf(float f) {
  union { float f; unsigned int u; } un; un.f = f;
  unsigned int r = un.u + 0x7fffu + ((un.u >> 16) & 1u);
  return (unsigned short)(r >> 16);
}

__device__ __forceinline__ float tanh_fast(float x) {
  x = fminf(15.f, fmaxf(-15.f, x));
  float e = __expf(2.f * x);
  return (e - 1.f) / (e + 1.f);
}

// async global->LDS, 16B per lane. lds dest must be wave-uniform base.
__device__ __forceinline__ void gload_lds16(const void* g, void* l) {
  __builtin_amdgcn_global_load_lds(
      (const __attribute__((address_space(1))) unsigned int*)(unsigned long long)g,
      (__attribute__((address_space(3))) unsigned int*)(unsigned int)(unsigned long long)l,
      16, 0, 0);
}

// ---------- convert kernels ----------
__global__ __launch_bounds__(256) void cvt_y_kernel(
    const float* __restrict__ x, unsigned short* __restrict__ y, int n4) {
  int i = blockIdx.x * blockDim.x + threadIdx.x;
  if (i < n4) {
    const float4 v = reinterpret_cast<const float4*>(x)[i];
    ushort4 o;
    o.x = f2bf(v.x); o.y = f2bf(v.y); o.z = f2bf(v.z); o.w = f2bf(v.w);
    reinterpret_cast<ushort4*>(y)[i] = o;
  }
}

// Wt[c][r] = bf16(W[r][c]); W is [R][ldW], use first C cols. Wt row-major [C][R].
__global__ __launch_bounds__(256) void cvt_transpose_kernel(
    const float* __restrict__ W, unsigned short* __restrict__ Wt,
    int R, int C, int ldW) {
  int i = blockIdx.x * blockDim.x + threadIdx.x;
  if (i < R * C) {
    int c = i / R, r = i - c * R;
    Wt[(size_t)c * R + r] = f2bf(W[(size_t)r * ldW + c]);
  }
}

// ---------- p0 kernel (null-token path) ----------
__global__ __launch_bounds__(512) void p0_kernel(
    const float* __restrict__ ynull, const float* __restrict__ W_trans,
    const float* __restrict__ b_trans, const float* __restrict__ W_p0,
    const float* __restrict__ b_p0, float* __restrict__ p0buf) {
  __shared__ float red[512];
  const int hh = threadIdx.x;
  float acc = 0.f;
  for (int e = 0; e < 512; ++e) acc = fmaf(ynull[e], W_trans[(size_t)e * 512 + hh], acc);
  const float ts = tanhf(acc + b_trans[hh]);
  red[hh] = ts * W_p0[hh];
  __syncthreads();
  for (int s = 256; s > 0; s >>= 1) {
    if (hh < s) red[hh] += red[hh + s];
    __syncthreads();
  }
  if (hh == 0) {
    const float z = red[0] + b_p0[0];
    const float p0 = 1.f / (1.f + __expf(-z));
    p0buf[0] = p0;
    p0buf[1] = 1.f - p0;
  }
}

// ---------- bf16 MFMA GEMM: C = epi(A @ Bt^T + bias) ----------
// A [M,K] bf16 row-major; Bt [N,K] bf16 row-major (i.e. B transposed).
// EPI 0: out bf16 = tanh(v);  EPI 1: out f32 = v.
// 128x128 tile, BK=32, 4 waves, m97-style 2-barrier loop with global_load_lds.
template <int EPI>
__global__ __launch_bounds__(256, 2) void gemm_tt(
    const unsigned short* __restrict__ A, const unsigned short* __restrict__ Bt,
    const float* __restrict__ bias, void* __restrict__ Cout,
    int M, int N, int K) {
  __shared__ unsigned short sA[128 * 32];
  __shared__ unsigned short sB[128 * 32];
  const int tid = threadIdx.x;
  const int lane = tid & 63;
  const int wave = tid >> 6;
  const int wr = wave >> 1, wc = wave & 1;
  const int m0 = blockIdx.x * 128, n0 = blockIdx.y * 128;

  f32x4 acc[4][4] = {};

  // staging geometry: chunk c covers rows [c*16, c*16+16), each lane 16B
  const int srow = lane >> 2;          // 0..15
  const int scol = (lane & 3) * 8;     // 0/8/16/24
  const int c0 = wave * 2, c1 = wave * 2 + 1;
  const unsigned short* Ar0 = A + (size_t)(m0 + c0 * 16 + srow) * K + scol;
  const unsigned short* Ar1 = A + (size_t)(m0 + c1 * 16 + srow) * K + scol;
  const unsigned short* Br0 = Bt + (size_t)(n0 + c0 * 16 + srow) * K + scol;
  const unsigned short* Br1 = Bt + (size_t)(n0 + c1 * 16 + srow) * K + scol;

  for (int kk = 0; kk < K; kk += 32) {
    __syncthreads();
    gload_lds16(Ar0 + kk, &sA[c0 * 512]);
    gload_lds16(Ar1 + kk, &sA[c1 * 512]);
    gload_lds16(Br0 + kk, &sB[c0 * 512]);
    gload_lds16(Br1 + kk, &sB[c1 * 512]);
    __syncthreads();
    bf16x8 af[4], bfr[4];
#pragma unroll
    for (int mi = 0; mi < 4; ++mi)
      af[mi] = *reinterpret_cast<const bf16x8*>(
          &sA[(wr * 64 + mi * 16 + (lane & 15)) * 32 + (lane >> 4) * 8]);
#pragma unroll
    for (int ni = 0; ni < 4; ++ni)
      bfr[ni] = *reinterpret_cast<const bf16x8*>(
          &sB[(wc * 64 + ni * 16 + (lane & 15)) * 32 + (lane >> 4) * 8]);
#pragma unroll
    for (int mi = 0; mi < 4; ++mi)
#pragma unroll
      for (int ni = 0; ni < 4; ++ni)
        acc[mi][ni] = __builtin_amdgcn_mfma_f32_16x16x32_bf16(
            af[mi], bfr[ni], acc[mi][ni], 0, 0, 0);
  }

  const int crow0 = m0 + wr * 64 + (lane >> 4) * 4;
  const int ccol0 = n0 + wc * 64 + (lane & 15);
#pragma unroll
  for (int mi = 0; mi < 4; ++mi) {
#pragma unroll
    for (int ni = 0; ni < 4; ++ni) {
      const int gcol = ccol0 + ni * 16;
      const float bv = bias[gcol];
#pragma unroll
      for (int r = 0; r < 4; ++r) {
        const int grow = crow0 + mi * 16 + r;
        const float v = acc[mi][ni][r] + bv;
        if constexpr (EPI == 0) {
          ((unsigned short*)Cout)[(size_t)grow * N + gcol] = f2bf(tanh_fast(v));
        } else {
          ((float*)Cout)[(size_t)grow * N + gcol] = v;
        }
      }
    }
  }
}

// ---------- windowed softmax -> jw [B][128][128] f32 ----------
// jw[b,i,k] = (1-p0) * softmax_k( logits[b*128+i, (128-i)+k] ), k in [0,128)
__global__ __launch_bounds__(256) void wsoftmax_kernel(
    const float* __restrict__ logits, const float* __restrict__ p0buf,
    float* __restrict__ jwout) {
  const int lane = threadIdx.x & 63;
  const int wave = threadIdx.x >> 6;
  const int row = blockIdx.x * 4 + wave;  // row = b*128 + i, < 32768
  const int i = row & 127;
  const float* lrow = logits + (size_t)row * 256 + (128 - i);
  const float v0 = lrow[lane];
  const float v1 = lrow[lane + 64];
  float mx = fmaxf(v0, v1);
#pragma unroll
  for (int off = 32; off > 0; off >>= 1) mx = fmaxf(mx, __shfl_xor(mx, off));
  const float e0 = __expf(v0 - mx);
  const float e1 = __expf(v1 - mx);
  float s = e0 + e1;
#pragma unroll
  for (int off = 32; off > 0; off >>= 1) s += __shfl_xor(s, off);
  const float scale = p0buf[1] / s;  // (1-p0)/sum
  float* orow = jwout + (size_t)row * 128;
  orow[lane] = e0 * scale;
  orow[lane + 64] = e1 * scale;
}

// ---------- HMM forward recursion over g = f[0:J] + f[J:2J] ----------
// g0[k] = e[k,0] + e[J+k,0]
// g'[k] = (sum_jj g[jj]*jw[jj,k]) * e[k,t] + g[k]*p0*e[J+k,t]
// out[b] = log(sum_{k<tlen} g_{slen-1}[k] + 1e-29)
__global__ __launch_bounds__(256, 1) void forward_hmm(
    const float* __restrict__ jw, const float* __restrict__ emission,
    const float* __restrict__ p0buf, const int* __restrict__ slen_p,
    const int* __restrict__ tlen_p, float* __restrict__ out) {
  __shared__ float gbuf[2][128];
  __shared__ float part[2][128];
  __shared__ float red[4];
  const int b = blockIdx.x;
  const int tid = threadIdx.x;
  const int k = tid & 127;
  const int h = tid >> 7;  // which half of jj range this thread sums
  const int lane = tid & 63;
  const int wave = tid >> 6;

  const float* eb = emission + (size_t)b * 256 * 64;

  // register-resident column slice of jw: jwreg[j] = jw[b][h*64+j][k]
  float jwreg[64];
  {
    const float* jb = jw + (size_t)b * 16384 + (size_t)(h * 64) * 128 + k;
#pragma unroll
    for (int j = 0; j < 64; ++j) jwreg[j] = jb[(size_t)j * 128];
  }
  const float p0 = p0buf[0];
  const int S = slen_p[b];
  const int T = tlen_p[b];

  if (h == 0) gbuf[0][k] = eb[k * 64] + eb[(128 + k) * 64];
  __syncthreads();

  const int steps = S - 1;
  int cur = 0;
  for (int t = 1; t <= steps; ++t) {
    float e0 = 0.f, e1 = 0.f;
    if (h == 0) {  // issue early; latency hides under the matvec below
      e0 = eb[k * 64 + t];
      e1 = eb[(128 + k) * 64 + t];
    }
    float acc = 0.f;
    const float* gv = &gbuf[cur][h * 64];
#pragma unroll
    for (int c = 0; c < 16; ++c) {
      const float4 g4 = *reinterpret_cast<const float4*>(&gv[c * 4]);
      acc = fmaf(g4.x, jwreg[c * 4 + 0], acc);
      acc = fmaf(g4.y, jwreg[c * 4 + 1], acc);
      acc = fmaf(g4.z, jwreg[c * 4 + 2], acc);
      acc = fmaf(g4.w, jwreg[c * 4 + 3], acc);
    }
    part[h][k] = acc;
    __syncthreads();
    if (h == 0) {
      const float s = part[0][k] + part[1][k];
      gbuf[cur ^ 1][k] = fmaf(s, e0, gbuf[cur][k] * p0 * e1);
    }
    __syncthreads();
    cur ^= 1;
  }

  float val = 0.f;
  if (h == 0 && k < T) val = gbuf[cur][k];
#pragma unroll
  for (int off = 32; off > 0; off >>= 1) val += __shfl_xor(val, off);
  if (lane == 0) red[wave] = val;
  __syncthreads();
  if (tid == 0) out[b] = logf(red[0] + red[1] + red[2] + red[3] + 1e-29f);
}

// ---------- launch ----------
extern "C" void kernel_launch(void* const* d_in, const int* in_sizes, int n_in,
                              void* d_out, int out_size, void* d_ws, size_t ws_size,
                              hipStream_t stream) {
  const float* y_hidden = (const float*)d_in[0];   // [256,128,512]
  const float* y_null   = (const float*)d_in[1];   // [1,1,512]
  const float* W_trans  = (const float*)d_in[2];   // [512,512]
  const float* b_trans  = (const float*)d_in[3];   // [512]
  const float* W_jump   = (const float*)d_in[4];   // [512,257]
  const float* b_jump   = (const float*)d_in[5];   // [257]
  const float* W_p0     = (const float*)d_in[6];   // [512,1]
  const float* b_p0     = (const float*)d_in[7];   // [1]
  const float* emission = (const float*)d_in[8];   // [256,256,64]
  const int* slen = (const int*)d_in[9];
  const int* tlen = (const int*)d_in[10];
  float* out = (float*)d_out;

  char* ws = (char*)d_ws;
  unsigned short* a16   = (unsigned short*)ws;               // 33,554,432 B
  float* logits         = (float*)ws;                        // alias a16 (dead after GEMM1)
  unsigned short* ts16  = (unsigned short*)(ws + 33554432);  // 33,554,432 B
  unsigned short* wt16t = (unsigned short*)(ws + 67108864);  // 524,288 B
  unsigned short* wj16t = (unsigned short*)(ws + 67633152);  // 262,144 B
  float* p0buf          = (float*)(ws + 67895296);           // 256 B
  float* jwbuf          = (float*)(ws + 67895552);           // 16,777,216 B
  // total ~84.7 MB

  // bf16 conversions (+ weight transposes for contiguous MFMA B-frags)
  cvt_y_kernel<<<dim3(16384), dim3(256), 0, stream>>>(y_hidden, a16, 16777216 / 4);
  cvt_transpose_kernel<<<dim3((512 * 512 + 255) / 256), dim3(256), 0, stream>>>(
      W_trans, wt16t, 512, 512, 512);
  cvt_transpose_kernel<<<dim3((512 * 256 + 255) / 256), dim3(256), 0, stream>>>(
      W_jump, wj16t, 512, 256, 257);
  p0_kernel<<<dim3(1), dim3(512), 0, stream>>>(y_null, W_trans, b_trans, W_p0, b_p0, p0buf);

  // GEMM1: ts = tanh(y @ W_trans + b_trans)  -> bf16 [32768,512]
  gemm_tt<0><<<dim3(256, 4), dim3(256), 0, stream>>>(a16, wt16t, b_trans, (void*)ts16,
                                                     32768, 512, 512);
  // GEMM2: logits = ts @ W_jump[:,0:256] + b_jump -> f32 [32768,256]
  gemm_tt<1><<<dim3(256, 2), dim3(256), 0, stream>>>(ts16, wj16t, b_jump, (void*)logits,
                                                     32768, 256, 512);
  // windowed softmax -> jw [256][128][128]
  wsoftmax_kernel<<<dim3(8192), dim3(256), 0, stream>>>(logits, p0buf, jwbuf);
  // HMM forward + masked log-sum
  forward_hmm<<<dim3(256), dim3(256), 0, stream>>>(jwbuf, emission, p0buf, slen, tlen, out);
}